// Round 1
// baseline (104.654 us; speedup 1.0000x reference)
//
#include <hip/hip_runtime.h>

#define BA 8192
#define DE 8192
#define LGRP 2048   // DE/4 groups per row
#define TPB 512     // threads per block; 2048/512 = 4 groups per thread

__global__ __launch_bounds__(TPB)
void multistrike_pool_kernel(const float* __restrict__ x, float* __restrict__ out) {
    __shared__ float b4[LGRP];   // 8 KB

    const int row = blockIdx.x;
    const float4* __restrict__ xrow =
        reinterpret_cast<const float4*>(x + (size_t)row * DE);
    float4* __restrict__ orow =
        reinterpret_cast<float4*>(out + (size_t)row * DE);

    float4 v[4];

    // Pass 1: coalesced float4 loads, block-of-4 sums into LDS.
    #pragma unroll
    for (int i = 0; i < 4; ++i) {
        const int g = i * TPB + (int)threadIdx.x;
        const float4 t = xrow[g];
        v[i] = t;
        b4[g] = (t.x + t.y) + (t.z + t.w);
    }
    __syncthreads();

    // Pass 2: combine register data + LDS b4 neighbors, coalesced float4 store.
    #pragma unroll
    for (int i = 0; i < 4; ++i) {
        const int g = i * TPB + (int)threadIdx.x;
        const float4 t = v[i];
        // boundary clamp: f2[g] = p16[g] for g <= L-4; f2[L-3+i] = p16[L-7+i]
        const int gc = (g >= LGRP - 3) ? (g - 4) : g;
        const float s16 = (b4[gc] + b4[gc + 1]) + (b4[gc + 2] + b4[gc + 3]);

        float4 o;
        o.x = 0.5f  * (t.x + t.y);        // p2 even
        o.y = 0.25f * b4[g];              // p4
        o.z = 0.5f  * (t.z + t.w);        // p2 odd
        o.w = s16 * (1.0f / 16.0f);       // f2 (k=16 pool, stride 4, clamped)
        orow[g] = o;
    }
}

extern "C" void kernel_launch(void* const* d_in, const int* in_sizes, int n_in,
                              void* d_out, int out_size, void* d_ws, size_t ws_size,
                              hipStream_t stream) {
    const float* x = (const float*)d_in[0];
    float* out = (float*)d_out;
    multistrike_pool_kernel<<<BA, TPB, 0, stream>>>(x, out);
}

// Round 3
// 95.831 us; speedup vs baseline: 1.0921x; 1.0921x over previous
//
#include <hip/hip_runtime.h>

#define BA 8192
#define DE 8192
#define LGRP 2048   // DE/4 groups per row
#define TPB 512     // threads per block; 2048/512 = 4 groups per thread

typedef float f32x4 __attribute__((ext_vector_type(4)));

__global__ __launch_bounds__(TPB)
void multistrike_pool_kernel(const float* __restrict__ x, float* __restrict__ out) {
    __shared__ float b4[LGRP];   // 8 KB

    const int row = blockIdx.x;
    const f32x4* __restrict__ xrow =
        reinterpret_cast<const f32x4*>(x + (size_t)row * DE);
    f32x4* __restrict__ orow =
        reinterpret_cast<f32x4*>(out + (size_t)row * DE);

    f32x4 v[4];

    // Pass 1: coalesced nontemporal float4 loads, block-of-4 sums into LDS.
    #pragma unroll
    for (int i = 0; i < 4; ++i) {
        const int g = i * TPB + (int)threadIdx.x;
        const f32x4 t = __builtin_nontemporal_load(&xrow[g]);
        v[i] = t;
        b4[g] = (t.x + t.y) + (t.z + t.w);
    }
    __syncthreads();

    // Pass 2: combine register data + LDS b4 neighbors, coalesced nt store.
    #pragma unroll
    for (int i = 0; i < 4; ++i) {
        const int g = i * TPB + (int)threadIdx.x;
        const f32x4 t = v[i];
        // boundary clamp: f2[g] = p16[g] for g <= L-4; f2[L-3+i] = p16[L-7+i]
        const int gc = (g >= LGRP - 3) ? (g - 4) : g;
        const float s16 = (b4[gc] + b4[gc + 1]) + (b4[gc + 2] + b4[gc + 3]);

        f32x4 o;
        o.x = 0.5f  * (t.x + t.y);        // p2 even
        o.y = 0.25f * b4[g];              // p4
        o.z = 0.5f  * (t.z + t.w);        // p2 odd
        o.w = s16 * (1.0f / 16.0f);       // f2 (k=16 pool, stride 4, clamped)
        __builtin_nontemporal_store(o, &orow[g]);
    }
}

extern "C" void kernel_launch(void* const* d_in, const int* in_sizes, int n_in,
                              void* d_out, int out_size, void* d_ws, size_t ws_size,
                              hipStream_t stream) {
    const float* x = (const float*)d_in[0];
    float* out = (float*)d_out;
    multistrike_pool_kernel<<<BA, TPB, 0, stream>>>(x, out);
}

// Round 4
// 90.086 us; speedup vs baseline: 1.1617x; 1.0638x over previous
//
#include <hip/hip_runtime.h>

#define BA   8192
#define DE   8192
#define LGRP 2048   // DE/4 groups per row
#define TPB  512    // 8 waves per block; each wave owns 256 groups
#define SEG  256    // groups per wave
#define LPW  260    // LDS floats per wave segment (256 + 3 overlap + 1 pad)

typedef float f32x4 __attribute__((ext_vector_type(4)));

__global__ __launch_bounds__(TPB)
void multistrike_pool_kernel(const float* __restrict__ x, float* __restrict__ out) {
    __shared__ float b4s[8][LPW];   // 8.3 KB, wave-private segments -> no barrier

    const int row = blockIdx.x;
    const int wav = (int)threadIdx.x >> 6;
    const int lan = (int)threadIdx.x & 63;
    const int gbase = wav * SEG;

    const f32x4* __restrict__ xrow =
        reinterpret_cast<const f32x4*>(x + (size_t)row * DE);
    f32x4* __restrict__ orow =
        reinterpret_cast<f32x4*>(out + (size_t)row * DE);

    float* bseg = b4s[wav];

    f32x4 v[4];

    // Pass 1: coalesced nt loads; block-of-4 sums into wave-private LDS.
    #pragma unroll
    for (int i = 0; i < 4; ++i) {
        const int gl = i * 64 + lan;
        const f32x4 t = __builtin_nontemporal_load(&xrow[gbase + gl]);
        v[i] = t;
        bseg[gl] = (t.x + t.y) + (t.z + t.w);
    }
    // Overlap: lanes 61-63 load next segment's first 3 groups (k=16 window).
    if (wav < 7 && lan >= 61) {
        const f32x4 t = __builtin_nontemporal_load(&xrow[gbase + SEG + (lan - 61)]);
        bseg[SEG + (lan - 61)] = (t.x + t.y) + (t.z + t.w);
    }
    // No __syncthreads: same-wave DS write->read is ordered; compiler emits
    // lgkmcnt waits for the may-aliasing reads below.

    // Pass 2: combine registers + wave-private b4, coalesced nt store.
    #pragma unroll
    for (int i = 0; i < 4; ++i) {
        const int gl = i * 64 + lan;
        const int g  = gbase + gl;
        const f32x4 t = v[i];
        // boundary clamp (only wav==7 reaches it): f2[g]=p16[g-4] for g>=L-3
        const int gcl = (g >= LGRP - 3) ? (gl - 4) : gl;
        const float s16 = (bseg[gcl] + bseg[gcl + 1]) + (bseg[gcl + 2] + bseg[gcl + 3]);

        f32x4 o;
        o.x = 0.5f  * (t.x + t.y);        // p2 even
        o.y = 0.25f * bseg[gl];           // p4
        o.z = 0.5f  * (t.z + t.w);        // p2 odd
        o.w = s16 * (1.0f / 16.0f);       // f2 (k=16 pool, stride 4, clamped)
        __builtin_nontemporal_store(o, &orow[g]);
    }
}

extern "C" void kernel_launch(void* const* d_in, const int* in_sizes, int n_in,
                              void* d_out, int out_size, void* d_ws, size_t ws_size,
                              hipStream_t stream) {
    const float* x = (const float*)d_in[0];
    float* out = (float*)d_out;
    multistrike_pool_kernel<<<BA, TPB, 0, stream>>>(x, out);
}